// Round 8
// baseline (196.575 us; speedup 1.0000x reference)
//
#include <hip/hip_runtime.h>

#define B_ 256
#define K_ 10
#define I_ 1152
#define O_ 16
#define C_ 8

static __device__ __forceinline__ unsigned short f32_bf16(float f) {
    unsigned int u = __float_as_uint(f);
    u += 0x7FFFu + ((u >> 16) & 1u);           // round-to-nearest-even
    return (unsigned short)(u >> 16);
}

// unpack uint2 (4 packed bf16) -> 4 floats
#define UNPACK4(P, F0, F1, F2, F3)                         \
    {                                                      \
        F0 = __uint_as_float((P).x << 16);                 \
        F1 = __uint_as_float((P).x & 0xffff0000u);         \
        F2 = __uint_as_float((P).y << 16);                 \
        F3 = __uint_as_float((P).y & 0xffff0000u);         \
    }

// ---------------------------------------------------------------------------
// uhat_kernel v3 (UNCHANGED — proven): u[b][k][i][o] = bf16(w·x)
// grid (72, 4, 5); 256 thr; 4 b per thread so each ds_read_b128 feeds 4 b.
// ---------------------------------------------------------------------------
__global__ __launch_bounds__(256) void uhat_kernel(
    const float* __restrict__ x, const float* __restrict__ w,
    unsigned short* __restrict__ u)
{
    __shared__ float w_lds[16 * 132];   // [ii][o*8+c], stride 132: 2-way max
    const int t   = threadIdx.x;
    const int i_l = t & 15, tg = t >> 4;
    const int i0  = blockIdx.x * 16;
    const int b0  = blockIdx.y * 64 + tg * 4;
    const int kb  = blockIdx.z * 2;
    const int i   = i0 + i_l;

    float4 xr[4][2];
#pragma unroll
    for (int bb = 0; bb < 4; bb++) {
        const float4* xp = (const float4*)(x + ((size_t)(b0 + bb) * I_ + i) * C_);
        xr[bb][0] = xp[0];
        xr[bb][1] = xp[1];
    }

#pragma unroll
    for (int kk = 0; kk < 2; kk++) {
        const int k = kb + kk;
        __syncthreads();
        const float4* ws = (const float4*)(w + ((size_t)k * I_ + i0) * O_ * C_);
#pragma unroll
        for (int r = 0; r < 2; r++) {
            int idx = r * 256 + t;               // float4 index in 16x128 slab
            int ii = idx >> 5, rem = idx & 31;
            *(float4*)&w_lds[ii * 132 + rem * 4] = ws[idx];
        }
        __syncthreads();

#pragma unroll
        for (int half = 0; half < 2; half++) {   // o 0..7 then 8..15
            unsigned int pk[4][4];
#pragma unroll
            for (int oq = 0; oq < 4; oq++) {
                const int oo = half * 4 + oq;    // o-pair index
                float d[4][2];
#pragma unroll
                for (int h = 0; h < 2; h++) {
                    const int o = oo * 2 + h;
                    const float4 w0 = *(const float4*)&w_lds[i_l * 132 + o * 8];
                    const float4 w1 = *(const float4*)&w_lds[i_l * 132 + o * 8 + 4];
#pragma unroll
                    for (int bb = 0; bb < 4; bb++) {
                        d[bb][h] = w0.x*xr[bb][0].x + w0.y*xr[bb][0].y
                                 + w0.z*xr[bb][0].z + w0.w*xr[bb][0].w
                                 + w1.x*xr[bb][1].x + w1.y*xr[bb][1].y
                                 + w1.z*xr[bb][1].z + w1.w*xr[bb][1].w;
                    }
                }
#pragma unroll
                for (int bb = 0; bb < 4; bb++)
                    pk[bb][oq] = (unsigned int)f32_bf16(d[bb][0]) |
                                 ((unsigned int)f32_bf16(d[bb][1]) << 16);
            }
#pragma unroll
            for (int bb = 0; bb < 4; bb++) {
                unsigned int* dst = (unsigned int*)
                    (u + (((size_t)(b0 + bb) * K_ + k) * I_ + i) * O_) + half * 4;
                *(uint4*)dst = make_uint4(pk[bb][0], pk[bb][1], pk[bb][2], pk[bb][3]);
            }
        }
    }
}

// ---------------------------------------------------------------------------
// sweep: one routing pass over ALL i (6 chunks of 192) for one b.
// thread: og = t&3 (o-quad), i_l = t>>2 in [0,192).
// ---------------------------------------------------------------------------
template <bool UNIFORM>
static __device__ __forceinline__ void sweep(
    const unsigned short* __restrict__ ub, int i_l,
    const float* __restrict__ v_lds, int og, float acc[K_][4])
{
#pragma unroll
    for (int k = 0; k < K_; k++)
#pragma unroll
        for (int j = 0; j < 4; j++) acc[k][j] = 0.f;

    uint2 P[K_], Q[K_];
#pragma unroll
    for (int k = 0; k < K_; k++)
        P[k] = *(const uint2*)(ub + ((size_t)k * I_ + i_l) * O_);

#pragma unroll
    for (int ic = 0; ic < 6; ic++) {
        if (ic + 1 < 6) {
            const int i = (ic + 1) * 192 + i_l;
#pragma unroll
            for (int k = 0; k < K_; k++)
                Q[k] = *(const uint2*)(ub + ((size_t)k * I_ + i) * O_);
        }
        float c[K_];
        if (!UNIFORM) {
            float l[K_];
#pragma unroll
            for (int k = 0; k < K_; k++) {
                float f0, f1, f2, f3;
                UNPACK4(P[k], f0, f1, f2, f3);
                const float* vk = &v_lds[k * 16 + og * 4];
                float lk = f0 * vk[0] + f1 * vk[1] + f2 * vk[2] + f3 * vk[3];
                lk += __shfl_xor(lk, 1);
                lk += __shfl_xor(lk, 2);
                l[k] = lk;
            }
            float m = l[0];
#pragma unroll
            for (int k = 1; k < K_; k++) m = fmaxf(m, l[k]);
            float Z = 0.f;
#pragma unroll
            for (int k = 0; k < K_; k++) { l[k] = __expf(l[k] - m); Z += l[k]; }
            const float inv = 1.0f / Z;
#pragma unroll
            for (int k = 0; k < K_; k++) c[k] = l[k] * inv;
        } else {
#pragma unroll
            for (int k = 0; k < K_; k++) c[k] = 1.0f;
        }
#pragma unroll
        for (int k = 0; k < K_; k++) {
            float f0, f1, f2, f3;
            UNPACK4(P[k], f0, f1, f2, f3);
            acc[k][0] = fmaf(c[k], f0, acc[k][0]);
            acc[k][1] = fmaf(c[k], f1, acc[k][1]);
            acc[k][2] = fmaf(c[k], f2, acc[k][2]);
            acc[k][3] = fmaf(c[k], f3, acc[k][3]);
        }
#pragma unroll
        for (int k = 0; k < K_; k++) P[k] = Q[k];
    }
}

// butterfly over the 16 i-lanes of each wave, deposit per-wave sums in red
static __device__ __forceinline__ void block_reduce(
    float acc[K_][4], float* __restrict__ red, int lane, int wv)
{
#pragma unroll
    for (int k = 0; k < K_; k++)
#pragma unroll
        for (int j = 0; j < 4; j++) {
            float a = acc[k][j];
            a += __shfl_xor(a, 4);  a += __shfl_xor(a, 8);
            a += __shfl_xor(a, 16); a += __shfl_xor(a, 32);
            acc[k][j] = a;
        }
    if (lane < 4) {
#pragma unroll
        for (int k = 0; k < K_; k++)
            *(float4*)&red[wv * 160 + k * 16 + lane * 4] =
                make_float4(acc[k][0], acc[k][1], acc[k][2], acc[k][3]);
    }
    __syncthreads();
}

// sum the 12 per-wave partials for element t (t < 160)
static __device__ __forceinline__ float sum12(const float* __restrict__ red, int t)
{
    float s = 0.f;
#pragma unroll
    for (int wgi = 0; wgi < 12; wgi++) s += red[wgi * 160 + t];
    return s;
}

// squash for element t<160: 16-lane o-group norm reduce
static __device__ __forceinline__ float squash_v(float s) {
    float n2 = s * s;
    n2 += __shfl_xor(n2, 1); n2 += __shfl_xor(n2, 2);
    n2 += __shfl_xor(n2, 4); n2 += __shfl_xor(n2, 8);
    const float norm = sqrtf(n2);
    return s * (n2 / (1.0f + n2) / (norm + 1e-9f));
}

// ---------------------------------------------------------------------------
// route_all: all 3 routing passes + squashes for one b in ONE block.
// grid (256), 768 thr = 12 waves = 1 block/CU.
// __launch_bounds__(768) ONLY — no min-waves arg.  Rounds 3 & 7 proved that
// (768,3) makes the compiler cap VGPRs at 84 (512/6) and spill ~160 MB of
// scratch; with the bare bound the cap is 512/3=168 and the ~120 regs this
// kernel needs stay resident.
// ---------------------------------------------------------------------------
__global__ __launch_bounds__(768) void route_all(
    const unsigned short* __restrict__ u, float* __restrict__ out)
{
    __shared__ float red[12 * 160];
    __shared__ float v_lds[160];
    __shared__ float v1_lds[160];

    const int t    = threadIdx.x;
    const int og   = t & 3, i_l = t >> 2;   // i_l in 0..191
    const int b    = blockIdx.x;
    const int lane = t & 63, wv = t >> 6;

    const unsigned short* ub = u + (size_t)b * K_ * I_ * O_ + og * 4;
    float acc[K_][4];

    // ---- pass 1: uniform c = 1/K ----
    sweep<true>(ub, i_l, nullptr, og, acc);
    block_reduce(acc, red, lane, wv);
    if (t < 160) {
        float v = squash_v(sum12(red, t) * (1.0f / K_));
        v1_lds[t] = v;
        v_lds[t]  = v;
    }
    __syncthreads();

    // ---- pass 2: logits from v1 ----
    sweep<false>(ub, i_l, v_lds, og, acc);
    block_reduce(acc, red, lane, wv);
    float v12 = 0.f;
    if (t < 160) v12 = v1_lds[t] + squash_v(sum12(red, t));
    __syncthreads();          // all sum12 reads done before v_lds overwrite
    if (t < 160) v_lds[t] = v12;
    __syncthreads();

    // ---- pass 3: logits from v1+v2 (telescoped) ----
    sweep<false>(ub, i_l, v_lds, og, acc);
    block_reduce(acc, red, lane, wv);
    if (t < 160)
        out[(size_t)b * 160 + t] = squash_v(sum12(red, t));
}

// ---------------------------------------------------------------------------
extern "C" void kernel_launch(void* const* d_in, const int* in_sizes, int n_in,
                              void* d_out, int out_size, void* d_ws, size_t ws_size,
                              hipStream_t stream)
{
    const float* x = (const float*)d_in[0];
    const float* w = (const float*)d_in[1];
    float* outp = (float*)d_out;

    unsigned short* u = (unsigned short*)d_ws;   // B*K*I*O bf16 = 94.4 MB

    uhat_kernel<<<dim3(72, 4, 5), 256, 0, stream>>>(x, w, u);
    route_all<<<B_, 768, 0, stream>>>(u, outp);
}

// Round 9
// 139.634 us; speedup vs baseline: 1.4078x; 1.4078x over previous
//
#include <hip/hip_runtime.h>

#define B_ 256
#define K_ 10
#define I_ 1152
#define O_ 16
#define C_ 8

static __device__ __forceinline__ unsigned short f32_bf16(float f) {
    unsigned int u = __float_as_uint(f);
    u += 0x7FFFu + ((u >> 16) & 1u);           // round-to-nearest-even
    return (unsigned short)(u >> 16);
}

// ---------------------------------------------------------------------------
// uhat_kernel v3 (UNCHANGED — proven): u[b][k][i][o] = bf16(w·x)
// grid (72, 4, 5); 256 thr; 4 b per thread so each ds_read_b128 feeds 4 b.
// ---------------------------------------------------------------------------
__global__ __launch_bounds__(256) void uhat_kernel(
    const float* __restrict__ x, const float* __restrict__ w,
    unsigned short* __restrict__ u)
{
    __shared__ float w_lds[16 * 132];   // [ii][o*8+c], stride 132: 2-way max
    const int t   = threadIdx.x;
    const int i_l = t & 15, tg = t >> 4;
    const int i0  = blockIdx.x * 16;
    const int b0  = blockIdx.y * 64 + tg * 4;
    const int kb  = blockIdx.z * 2;
    const int i   = i0 + i_l;

    float4 xr[4][2];
#pragma unroll
    for (int bb = 0; bb < 4; bb++) {
        const float4* xp = (const float4*)(x + ((size_t)(b0 + bb) * I_ + i) * C_);
        xr[bb][0] = xp[0];
        xr[bb][1] = xp[1];
    }

#pragma unroll
    for (int kk = 0; kk < 2; kk++) {
        const int k = kb + kk;
        __syncthreads();
        const float4* ws = (const float4*)(w + ((size_t)k * I_ + i0) * O_ * C_);
#pragma unroll
        for (int r = 0; r < 2; r++) {
            int idx = r * 256 + t;               // float4 index in 16x128 slab
            int ii = idx >> 5, rem = idx & 31;
            *(float4*)&w_lds[ii * 132 + rem * 4] = ws[idx];
        }
        __syncthreads();

#pragma unroll
        for (int half = 0; half < 2; half++) {   // o 0..7 then 8..15
            unsigned int pk[4][4];
#pragma unroll
            for (int oq = 0; oq < 4; oq++) {
                const int oo = half * 4 + oq;    // o-pair index
                float d[4][2];
#pragma unroll
                for (int h = 0; h < 2; h++) {
                    const int o = oo * 2 + h;
                    const float4 w0 = *(const float4*)&w_lds[i_l * 132 + o * 8];
                    const float4 w1 = *(const float4*)&w_lds[i_l * 132 + o * 8 + 4];
#pragma unroll
                    for (int bb = 0; bb < 4; bb++) {
                        d[bb][h] = w0.x*xr[bb][0].x + w0.y*xr[bb][0].y
                                 + w0.z*xr[bb][0].z + w0.w*xr[bb][0].w
                                 + w1.x*xr[bb][1].x + w1.y*xr[bb][1].y
                                 + w1.z*xr[bb][1].z + w1.w*xr[bb][1].w;
                    }
                }
#pragma unroll
                for (int bb = 0; bb < 4; bb++)
                    pk[bb][oq] = (unsigned int)f32_bf16(d[bb][0]) |
                                 ((unsigned int)f32_bf16(d[bb][1]) << 16);
            }
#pragma unroll
            for (int bb = 0; bb < 4; bb++) {
                unsigned int* dst = (unsigned int*)
                    (u + (((size_t)(b0 + bb) * K_ + k) * I_ + i) * O_) + half * 4;
                *(uint4*)dst = make_uint4(pk[bb][0], pk[bb][1], pk[bb][2], pk[bb][3]);
            }
        }
    }
}

// ---------------------------------------------------------------------------
// sweep v2 (o-pair mapping, ~65 VGPR): one routing pass over all i for one b.
// thread: og = t&7 (owns o = og*2, og*2+1), i_l = t>>3 in [0,96); 12 chunks.
// Per-k load is 4 B (one packed bf16 pair); 64 lanes cover 256 contiguous B.
// ---------------------------------------------------------------------------
template <bool UNIFORM>
static __device__ __forceinline__ void sweep(
    const unsigned short* __restrict__ ub, int i_l,
    const float* __restrict__ v_lds, int og, float acc[K_][2])
{
#pragma unroll
    for (int k = 0; k < K_; k++) { acc[k][0] = 0.f; acc[k][1] = 0.f; }

    unsigned int P[K_], Q[K_];
#pragma unroll
    for (int k = 0; k < K_; k++)
        P[k] = *(const unsigned int*)(ub + ((size_t)k * I_ + i_l) * O_);

#pragma unroll 1                          // keep regs low; body is big enough
    for (int ic = 0; ic < 12; ic++) {
        if (ic + 1 < 12) {
            const int i = (ic + 1) * 96 + i_l;
#pragma unroll
            for (int k = 0; k < K_; k++)
                Q[k] = *(const unsigned int*)(ub + ((size_t)k * I_ + i) * O_);
        }
        float c[K_];
        if (!UNIFORM) {
            float l[K_];
#pragma unroll
            for (int k = 0; k < K_; k++) {
                const float f0 = __uint_as_float(P[k] << 16);
                const float f1 = __uint_as_float(P[k] & 0xffff0000u);
                float lk = f0 * v_lds[k * 16 + og * 2]
                         + f1 * v_lds[k * 16 + og * 2 + 1];
                lk += __shfl_xor(lk, 1);
                lk += __shfl_xor(lk, 2);
                lk += __shfl_xor(lk, 4);
                l[k] = lk;
            }
            float m = l[0];
#pragma unroll
            for (int k = 1; k < K_; k++) m = fmaxf(m, l[k]);
            float Z = 0.f;
#pragma unroll
            for (int k = 0; k < K_; k++) { l[k] = __expf(l[k] - m); Z += l[k]; }
            const float inv = 1.0f / Z;
#pragma unroll
            for (int k = 0; k < K_; k++) c[k] = l[k] * inv;
        } else {
#pragma unroll
            for (int k = 0; k < K_; k++) c[k] = 1.0f;
        }
#pragma unroll
        for (int k = 0; k < K_; k++) {
            const float f0 = __uint_as_float(P[k] << 16);
            const float f1 = __uint_as_float(P[k] & 0xffff0000u);
            acc[k][0] = fmaf(c[k], f0, acc[k][0]);
            acc[k][1] = fmaf(c[k], f1, acc[k][1]);
        }
#pragma unroll
        for (int k = 0; k < K_; k++) P[k] = Q[k];
    }
}

// reduce acc over the 8 i-positions of each wave; deposit per-wave sums.
// After xor 8/16/32, lanes 0..7 hold the wave sums for og = lane.
static __device__ __forceinline__ void block_reduce(
    float acc[K_][2], float* __restrict__ red, int lane, int wv)
{
#pragma unroll
    for (int k = 0; k < K_; k++)
#pragma unroll
        for (int j = 0; j < 2; j++) {
            float a = acc[k][j];
            a += __shfl_xor(a, 8); a += __shfl_xor(a, 16); a += __shfl_xor(a, 32);
            acc[k][j] = a;
        }
    if (lane < 8) {
#pragma unroll
        for (int k = 0; k < K_; k++)
            *(float2*)&red[wv * 160 + k * 16 + lane * 2] =
                make_float2(acc[k][0], acc[k][1]);
    }
    __syncthreads();
}

// sum the 12 per-wave partials for element t (t < 160)
static __device__ __forceinline__ float sum12(const float* __restrict__ red, int t)
{
    float s = 0.f;
#pragma unroll
    for (int wgi = 0; wgi < 12; wgi++) s += red[wgi * 160 + t];
    return s;
}

// squash for element t<160: 16-lane o-group norm reduce
static __device__ __forceinline__ float squash_v(float s) {
    float n2 = s * s;
    n2 += __shfl_xor(n2, 1); n2 += __shfl_xor(n2, 2);
    n2 += __shfl_xor(n2, 4); n2 += __shfl_xor(n2, 8);
    const float norm = sqrtf(n2);
    return s * (n2 / (1.0f + n2) / (norm + 1e-9f));
}

// ---------------------------------------------------------------------------
// route_all v2: all 3 routing passes + squashes for one b in ONE block.
// grid (256), 768 thr = 12 waves.  o-pair mapping keeps the sweep at ~65
// VGPR so it fits the compiler's hard 84-reg cap for 768-thr blocks
// (rounds 3/7/8: demand ~110 -> 160 MB scratch spill at VGPR_Count=84).
// ---------------------------------------------------------------------------
__global__ __launch_bounds__(768) void route_all(
    const unsigned short* __restrict__ u, float* __restrict__ out)
{
    __shared__ float red[12 * 160];
    __shared__ float v_lds[160];
    __shared__ float v1_lds[160];

    const int t    = threadIdx.x;
    const int og   = t & 7, i_l = t >> 3;   // og: o-pair, i_l in 0..95
    const int b    = blockIdx.x;
    const int lane = t & 63, wv = t >> 6;

    const unsigned short* ub = u + (size_t)b * K_ * I_ * O_ + og * 2;
    float acc[K_][2];

    // ---- pass 1: uniform c = 1/K ----
    sweep<true>(ub, i_l, nullptr, og, acc);
    block_reduce(acc, red, lane, wv);
    if (t < 160) {
        float v = squash_v(sum12(red, t) * (1.0f / K_));
        v1_lds[t] = v;
        v_lds[t]  = v;
    }
    __syncthreads();

    // ---- pass 2: logits from v1 ----
    sweep<false>(ub, i_l, v_lds, og, acc);
    block_reduce(acc, red, lane, wv);
    float v12 = 0.f;
    if (t < 160) v12 = v1_lds[t] + squash_v(sum12(red, t));
    __syncthreads();          // all sum12 reads done before v_lds overwrite
    if (t < 160) v_lds[t] = v12;
    __syncthreads();

    // ---- pass 3: logits from v1+v2 (telescoped) ----
    sweep<false>(ub, i_l, v_lds, og, acc);
    block_reduce(acc, red, lane, wv);
    if (t < 160)
        out[(size_t)b * 160 + t] = squash_v(sum12(red, t));
}

// ---------------------------------------------------------------------------
extern "C" void kernel_launch(void* const* d_in, const int* in_sizes, int n_in,
                              void* d_out, int out_size, void* d_ws, size_t ws_size,
                              hipStream_t stream)
{
    const float* x = (const float*)d_in[0];
    const float* w = (const float*)d_in[1];
    float* outp = (float*)d_out;

    unsigned short* u = (unsigned short*)d_ws;   // B*K*I*O bf16 = 94.4 MB

    uhat_kernel<<<dim3(72, 4, 5), 256, 0, stream>>>(x, w, u);
    route_all<<<B_, 768, 0, stream>>>(u, outp);
}